// Round 3
// baseline (808.019 us; speedup 1.0000x reference)
//
#include <hip/hip_runtime.h>
#include <hip/hip_bf16.h>

// Problem constants
#define B_    32
#define C_    256
#define HW_   3136   // 56*56
#define OC_   256
#define M_    8
#define KPB_  589824 // per-sample wl shorts: 72 kblocks * 8192

typedef short v8s __attribute__((ext_vector_type(8)));   // 8 x bf16 (4 VGPRs)
typedef float f32x4 __attribute__((ext_vector_type(4)));

union bf8pack { v8s v; __hip_bfloat16 h[8]; };

__device__ __forceinline__ void gll16(const short* src, short* dst) {
    __builtin_amdgcn_global_load_lds((const __attribute__((address_space(1))) void*)src,
                                     (__attribute__((address_space(3))) void*)dst, 16, 0, 0);
}

// ---------------------------------------------------------------------------
// 0) zero the gap accumulator (ws is poisoned 0xAA before every launch)
__global__ void zero_gap_kernel(float* __restrict__ gap) {
    gap[blockIdx.x * 256 + threadIdx.x] = 0.f;
}

// ---------------------------------------------------------------------------
// 1) x (f32, BCHW) -> xg (bf16, [b][ib=8][p][32] channel-blocked), fused GAP.
__global__ __launch_bounds__(256) void xcast_kernel(const float* __restrict__ x,
                                                    short* __restrict__ xg,
                                                    float* __restrict__ gap) {
    __shared__ __hip_bfloat16 tile[64][65];   // [channel][pixel], +1 pad
    int b = blockIdx.z, ct = blockIdx.y, pt = blockIdx.x;
    int p0 = pt*64, c0 = ct*64;
    int tp = threadIdx.x & 63, tc = threadIdx.x >> 6;
    const float* xb = x + ((size_t)b*C_ + c0) * HW_ + p0;
    #pragma unroll
    for (int j = 0; j < 16; ++j) {
        int cl = tc + j*4;
        float v = xb[(size_t)cl*HW_ + tp];
        tile[cl][tp] = __float2bfloat16(v);
        float s = v;
        #pragma unroll
        for (int off = 32; off; off >>= 1) s += __shfl_xor(s, off, 64);
        if (tp == 0) atomicAdd(&gap[b*C_ + c0 + cl], s);
    }
    __syncthreads();
    #pragma unroll
    for (int it = 0; it < 2; ++it) {
        int idx = it*256 + threadIdx.x;
        int px = idx >> 3, ck = idx & 7;
        bf8pack pk;
        #pragma unroll
        for (int j = 0; j < 8; ++j) pk.h[j] = tile[ck*8 + j][px];
        int c = c0 + ck*8;
        size_t dst = (((size_t)b*8 + (c >> 5))*HW_ + p0 + px)*32 + (c & 31);
        *(v8s*)(xg + dst) = pk.v;
    }
}

// ---------------------------------------------------------------------------
// 2) Gate softmax + combined bias, fused. One wave per sample. gap holds SUMS.
__global__ void alpha_kernel(const float* __restrict__ gap,
                             const float* __restrict__ gate_w,
                             const float* __restrict__ gate_b,
                             const float* __restrict__ bias,
                             float* __restrict__ alpha,
                             float* __restrict__ biasc) {
    int b = blockIdx.x, lane = threadIdx.x;
    const float inv = 1.0f / HW_;
    float g0 = gap[b*C_ + lane]*inv,       g1 = gap[b*C_ + 64 + lane]*inv;
    float g2 = gap[b*C_ + 128 + lane]*inv, g3 = gap[b*C_ + 192 + lane]*inv;
    float logit[M_];
    #pragma unroll
    for (int m = 0; m < M_; ++m) {
        const float* w = gate_w + m*C_;
        float s = g0*w[lane] + g1*w[64+lane] + g2*w[128+lane] + g3*w[192+lane];
        for (int off = 32; off; off >>= 1) s += __shfl_xor(s, off, 64);
        logit[m] = s + gate_b[m];
    }
    float mx = logit[0];
    #pragma unroll
    for (int m = 1; m < M_; ++m) mx = fmaxf(mx, logit[m]);
    float den = 0.f, e[M_];
    #pragma unroll
    for (int m = 0; m < M_; ++m) { e[m] = __expf(logit[m] - mx); den += e[m]; }
    float am[M_];
    #pragma unroll
    for (int m = 0; m < M_; ++m) am[m] = e[m] / den;
    if (lane < M_) alpha[b*M_ + lane] = am[lane];
    #pragma unroll
    for (int r = 0; r < 4; ++r) {
        int o = r*64 + lane;
        float s = 0.f;
        #pragma unroll
        for (int m = 0; m < M_; ++m) s += am[m] * bias[m*OC_ + o];
        biasc[b*OC_ + o] = s;
    }
}

// ---------------------------------------------------------------------------
// 3) Combine expert kernels: wl[b][ib(8)][tap(9)][o(256)][i_in(32)] bf16.
//    (reverted to round-1 form: the 4-way b-split showed no gain)
__global__ __launch_bounds__(256) void combine_kernel(const float* __restrict__ weight,
                                                      const float* __restrict__ alpha,
                                                      short* __restrict__ wl) {
    __shared__ float as[B_*M_];
    as[threadIdx.x] = alpha[threadIdx.x];
    __syncthreads();
    int gc  = blockIdx.x*256 + threadIdx.x;   // [0, 73728)
    int i8  = gc & 3;
    int o   = (gc >> 2) & 255;
    int t2  = gc >> 10;
    int tap = t2 % 9;
    int ib  = t2 / 9;
    int base = o*2304 + (ib*32 + i8*8)*9 + tap;   // + j*9
    float wv[M_][8];
    #pragma unroll
    for (int m = 0; m < M_; ++m)
        #pragma unroll
        for (int j = 0; j < 8; ++j)
            wv[m][j] = weight[(size_t)m*589824 + base + j*9];
    for (int b = 0; b < B_; ++b) {
        bf8pack pk;
        #pragma unroll
        for (int j = 0; j < 8; ++j) {
            float s = 0.f;
            #pragma unroll
            for (int m = 0; m < M_; ++m) s += as[b*M_+m] * wv[m][j];
            pk.h[j] = __float2bfloat16(s);
        }
        *(v8s*)(wl + (size_t)b*KPB_ + (size_t)gc*8) = pk.v;
    }
}

// ---------------------------------------------------------------------------
// 4) Implicit-GEMM conv, MFMA bf16 16x16x32. BARRIER-LIGHT SCHEDULE.
//    Block = 256o x 224px, 4 waves; wave = 64o x 224px, acc[4][14].
//    KEY: waves split o only -> each wave's A quarter (64o x 32i = 4KB) is
//    CONTIGUOUS in wl. Each wave stages its OWN quarter via global_load_lds,
//    so A needs NO barrier: wave-local counted vmcnt + triple buffer staged
//    2-ahead. Only B (shared 384-px halo, single 24KB buffer) syncs: 2
//    barriers per 9 taps. Barriers: 72/block -> 15/block.
//    Per-tap mask applied as predicated LDS ADDRESS (cndmask to a zeroed
//    16B region) instead of a 4-VGPR operand select.
//    LDS 72.03 KB -> 2 blocks/CU: decoupled sibling block fills stalls.
__global__ __launch_bounds__(256, 2) void conv_kernel(const short* __restrict__ xg,
                                                      const short* __restrict__ wl,
                                                      const float* __restrict__ biasc,
                                                      float* __restrict__ out) {
    // shorts: A0@0, A1@8192, A2@16384, B@24576 (12288), zero@36864 (16)
    __shared__ short smem[36880];

    // T1: XCD swizzle, 448 = 8*56 bijective. Consecutive swz share sample b
    // -> wl[b] k-stream gets 14x same-XCD L2 reuse.
    const int wg  = blockIdx.x;
    const int swz = (wg & 7) * 56 + (wg >> 3);
    const int b   = swz / 14;
    const int pt  = swz - b * 14;

    const int tid = threadIdx.x;
    const int wave = tid >> 6, lane = tid & 63, q = lane >> 4, ln = lane & 15;
    const int P0 = pt * 224;

    const int DOFF[9] = {-57,-56,-55,-1,0,1,55,56,57};

    unsigned vmask[14];
    #pragma unroll
    for (int c = 0; c < 14; ++c) {
        int p = P0 + c*16 + ln;              // always < 3136
        int h = p/56, w = p%56;
        unsigned m = 0;
        #pragma unroll
        for (int tap = 0; tap < 9; ++tap) {
            int h2 = h + tap/3 - 1, w2 = w + tap%3 - 1;
            if ((unsigned)h2 < 56u && (unsigned)w2 < 56u) m |= (1u << tap);
        }
        vmask[c] = m;
    }

    // per-wave A quarter: o rows [wave*64, wave*64+64) = shorts [wave*2048, +2048)
    const short* wbase = wl + (size_t)b*KPB_ + wave*2048 + lane*8;
    const short* xbase = xg + (size_t)(b*8)*HW_*32;

    auto stageA = [&](int kidx, int buf) {   // 4 vmcnt events, wave-local
        const short* src = wbase + (size_t)kidx*8192;
        short* dst = &smem[buf*8192 + wave*2048 + lane*8];
        #pragma unroll
        for (int r = 0; r < 4; ++r) gll16(src + r*512, dst + r*512);
    };
    auto stageB = [&](int ib) {              // 6 vmcnt events, cooperative
        const short* src = xbase + ((long)ib*HW_ + P0 - 64)*32 + tid*8;
        short* dst = &smem[24576 + tid*8];
        #pragma unroll
        for (int r = 0; r < 6; ++r) gll16(src + r*2048, dst + r*2048);
    };

    f32x4 acc[4][14];
    #pragma unroll
    for (int r = 0; r < 4; ++r)
        #pragma unroll
        for (int c = 0; c < 14; ++c) acc[r][c] = (f32x4){0.f,0.f,0.f,0.f};

    // zero region for masked B reads
    if (tid == 0) { *(v8s*)&smem[36864] = (v8s){}; *(v8s*)&smem[36872] = (v8s){}; }

    // Prologue: B0(6), A0(4), A1(4). vmcnt(4): B0+A0 done, A1 in flight.
    stageB(0);
    stageA(0, 0);
    stageA(1, 1);
    asm volatile("s_waitcnt vmcnt(4) lgkmcnt(0)" ::: "memory");
    __builtin_amdgcn_s_barrier();
    asm volatile("" ::: "memory");

    const int a_off = wave*2048 + ln*32 + q*8;       // + (tap%3)*8192 + r*512
    int bcol[14];
    #pragma unroll
    for (int c = 0; c < 14; ++c) bcol[c] = 24576 + (64 + ln)*32 + q*8 + c*512;
    const int zoff = 36864;

    for (int ib = 0; ib < 8; ++ib) {
        #pragma unroll
        for (int tap = 0; tap < 9; ++tap) {
            const int k = ib*9 + tap;   // A buffer index: k%3 == tap%3

            if (tap == 0 && ib > 0) {
                // B turnover: all waves done reading old B (their ds_reads
                // retired before their MFMAs of iter k-1) -> barrier, restage.
                __builtin_amdgcn_s_barrier();
                asm volatile("" ::: "memory");
                stageB(ib);
                stageA(k + 2, (tap + 2) % 3);
                // need B(ib) + A(k) done; keep only A(k+2) (4 ev) in flight
                asm volatile("s_waitcnt vmcnt(4)" ::: "memory");
                __builtin_amdgcn_s_barrier();
                asm volatile("" ::: "memory");       // publish B cross-wave
            } else {
                if (k + 2 < 72) {
                    stageA(k + 2, (tap + 2) % 3);
                    // in flight: A(k+1)(4) + A(k+2)(4); waits A(k) complete
                    asm volatile("s_waitcnt vmcnt(8)" ::: "memory");
                } else if (k == 70) {
                    asm volatile("s_waitcnt vmcnt(4)" ::: "memory");
                } else { // k == 71
                    asm volatile("s_waitcnt vmcnt(0)" ::: "memory");
                }
            }
            __builtin_amdgcn_sched_barrier(0);

            v8s a[4];
            #pragma unroll
            for (int r = 0; r < 4; ++r)
                a[r] = *(const v8s*)&smem[(tap % 3)*8192 + a_off + r*512];

            const int doff32 = DOFF[tap]*32;
            __builtin_amdgcn_s_setprio(1);
            #pragma unroll
            for (int c = 0; c < 14; ++c) {
                int off = ((vmask[c] >> tap) & 1) ? (bcol[c] + doff32) : zoff;
                v8s v = *(const v8s*)&smem[off];
                #pragma unroll
                for (int r = 0; r < 4; ++r)
                    acc[r][c] = __builtin_amdgcn_mfma_f32_16x16x32_bf16(a[r], v, acc[r][c], 0, 0, 0);
            }
            __builtin_amdgcn_s_setprio(0);
        }
    }

    // Epilogue: D col=lane&15 (px), row=q*4+reg (o). No bounds checks needed.
    const int o0 = wave*64 + q*4;
    #pragma unroll
    for (int c = 0; c < 14; ++c) {
        int p = P0 + c*16 + ln;
        float* op = out + (size_t)b * OC_ * HW_ + p;
        #pragma unroll
        for (int r = 0; r < 4; ++r) {
            #pragma unroll
            for (int reg = 0; reg < 4; ++reg) {
                int o = o0 + r*16 + reg;
                op[(size_t)o * HW_] = acc[r][c][reg] + biasc[b*OC_ + o];
            }
        }
    }
}

// ---------------------------------------------------------------------------
extern "C" void kernel_launch(void* const* d_in, const int* in_sizes, int n_in,
                              void* d_out, int out_size, void* d_ws, size_t ws_size,
                              hipStream_t stream) {
    const float* x      = (const float*)d_in[0];
    const float* weight = (const float*)d_in[1];
    const float* bias   = (const float*)d_in[2];
    const float* gate_w = (const float*)d_in[3];
    const float* gate_b = (const float*)d_in[4];
    float* out = (float*)d_out;

    // Workspace layout (bytes):
    //   gap   @ 0       : 32,768
    //   biasc @ 32768   : 32,768
    //   alpha @ 65536   : 1,024
    //   (pad — absorbs conv's B-halo negative overrun, up to -4 KB)
    //   xg    @ 131072  : 32*8*3136*32*2 = 51,380,224
    //   wl    @ 51,511,296 : 32*589824*2 = 37,748,736 (absorbs B-halo tail overrun)
    char* ws = (char*)d_ws;
    float* gap   = (float*)(ws);
    float* biasc = (float*)(ws + 32768);
    float* alpha = (float*)(ws + 65536);
    short* xg    = (short*)(ws + 131072);
    short* wl    = (short*)(ws + 51511296);

    zero_gap_kernel<<<32, 256, 0, stream>>>(gap);
    xcast_kernel   <<<dim3(49, 4, 32), 256, 0, stream>>>(x, xg, gap);
    alpha_kernel   <<<32,  64, 0, stream>>>(gap, gate_w, gate_b, bias, alpha, biasc);
    combine_kernel <<<288, 256, 0, stream>>>(weight, alpha, wl);
    conv_kernel    <<<448, 256, 0, stream>>>(xg, wl, biasc, out);
}

// Round 5
// 506.101 us; speedup vs baseline: 1.5966x; 1.5966x over previous
//
#include <hip/hip_runtime.h>
#include <hip/hip_bf16.h>

// Problem constants
#define B_    32
#define C_    256
#define HW_   3136   // 56*56
#define OC_   256
#define M_    8
#define KPB_  589824 // per-sample wl shorts: 72 kblocks * 8192

typedef short v8s __attribute__((ext_vector_type(8)));   // 8 x bf16 (4 VGPRs)
typedef float f32x4 __attribute__((ext_vector_type(4)));

union bf8pack { v8s v; __hip_bfloat16 h[8]; };

__device__ __forceinline__ void gll16(const short* src, short* dst) {
    __builtin_amdgcn_global_load_lds((const __attribute__((address_space(1))) void*)src,
                                     (__attribute__((address_space(3))) void*)dst, 16, 0, 0);
}

// ---------------------------------------------------------------------------
// 0) zero the gap accumulator (ws is poisoned 0xAA before every launch)
__global__ void zero_gap_kernel(float* __restrict__ gap) {
    gap[blockIdx.x * 256 + threadIdx.x] = 0.f;
}

// ---------------------------------------------------------------------------
// 1) x (f32, BCHW) -> xg (bf16, [b][ib=8][p][32] channel-blocked), fused GAP.
__global__ __launch_bounds__(256) void xcast_kernel(const float* __restrict__ x,
                                                    short* __restrict__ xg,
                                                    float* __restrict__ gap) {
    __shared__ __hip_bfloat16 tile[64][65];   // [channel][pixel], +1 pad
    int b = blockIdx.z, ct = blockIdx.y, pt = blockIdx.x;
    int p0 = pt*64, c0 = ct*64;
    int tp = threadIdx.x & 63, tc = threadIdx.x >> 6;
    const float* xb = x + ((size_t)b*C_ + c0) * HW_ + p0;
    #pragma unroll
    for (int j = 0; j < 16; ++j) {
        int cl = tc + j*4;
        float v = xb[(size_t)cl*HW_ + tp];
        tile[cl][tp] = __float2bfloat16(v);
        float s = v;
        #pragma unroll
        for (int off = 32; off; off >>= 1) s += __shfl_xor(s, off, 64);
        if (tp == 0) atomicAdd(&gap[b*C_ + c0 + cl], s);
    }
    __syncthreads();
    #pragma unroll
    for (int it = 0; it < 2; ++it) {
        int idx = it*256 + threadIdx.x;
        int px = idx >> 3, ck = idx & 7;
        bf8pack pk;
        #pragma unroll
        for (int j = 0; j < 8; ++j) pk.h[j] = tile[ck*8 + j][px];
        int c = c0 + ck*8;
        size_t dst = (((size_t)b*8 + (c >> 5))*HW_ + p0 + px)*32 + (c & 31);
        *(v8s*)(xg + dst) = pk.v;
    }
}

// ---------------------------------------------------------------------------
// 2) Gate softmax + combined bias, fused. One wave per sample. gap holds SUMS.
__global__ void alpha_kernel(const float* __restrict__ gap,
                             const float* __restrict__ gate_w,
                             const float* __restrict__ gate_b,
                             const float* __restrict__ bias,
                             float* __restrict__ alpha,
                             float* __restrict__ biasc) {
    int b = blockIdx.x, lane = threadIdx.x;
    const float inv = 1.0f / HW_;
    float g0 = gap[b*C_ + lane]*inv,       g1 = gap[b*C_ + 64 + lane]*inv;
    float g2 = gap[b*C_ + 128 + lane]*inv, g3 = gap[b*C_ + 192 + lane]*inv;
    float logit[M_];
    #pragma unroll
    for (int m = 0; m < M_; ++m) {
        const float* w = gate_w + m*C_;
        float s = g0*w[lane] + g1*w[64+lane] + g2*w[128+lane] + g3*w[192+lane];
        for (int off = 32; off; off >>= 1) s += __shfl_xor(s, off, 64);
        logit[m] = s + gate_b[m];
    }
    float mx = logit[0];
    #pragma unroll
    for (int m = 1; m < M_; ++m) mx = fmaxf(mx, logit[m]);
    float den = 0.f, e[M_];
    #pragma unroll
    for (int m = 0; m < M_; ++m) { e[m] = __expf(logit[m] - mx); den += e[m]; }
    float am[M_];
    #pragma unroll
    for (int m = 0; m < M_; ++m) am[m] = e[m] / den;
    if (lane < M_) alpha[b*M_ + lane] = am[lane];
    #pragma unroll
    for (int r = 0; r < 4; ++r) {
        int o = r*64 + lane;
        float s = 0.f;
        #pragma unroll
        for (int m = 0; m < M_; ++m) s += am[m] * bias[m*OC_ + o];
        biasc[b*OC_ + o] = s;
    }
}

// ---------------------------------------------------------------------------
// 3) Combine expert kernels: wl[b][ib(8)][tap(9)][o(256)][i_in(32)] bf16.
__global__ __launch_bounds__(256) void combine_kernel(const float* __restrict__ weight,
                                                      const float* __restrict__ alpha,
                                                      short* __restrict__ wl) {
    __shared__ float as[B_*M_];
    as[threadIdx.x] = alpha[threadIdx.x];
    __syncthreads();
    int gc  = blockIdx.x*256 + threadIdx.x;   // [0, 73728)
    int i8  = gc & 3;
    int o   = (gc >> 2) & 255;
    int t2  = gc >> 10;
    int tap = t2 % 9;
    int ib  = t2 / 9;
    int base = o*2304 + (ib*32 + i8*8)*9 + tap;   // + j*9
    float wv[M_][8];
    #pragma unroll
    for (int m = 0; m < M_; ++m)
        #pragma unroll
        for (int j = 0; j < 8; ++j)
            wv[m][j] = weight[(size_t)m*589824 + base + j*9];
    for (int b = 0; b < B_; ++b) {
        bf8pack pk;
        #pragma unroll
        for (int j = 0; j < 8; ++j) {
            float s = 0.f;
            #pragma unroll
            for (int m = 0; m < M_; ++m) s += as[b*M_+m] * wv[m][j];
            pk.h[j] = __float2bfloat16(s);
        }
        *(v8s*)(wl + (size_t)b*KPB_ + (size_t)gc*8) = pk.v;
    }
}

// ---------------------------------------------------------------------------
// 4) Implicit-GEMM conv, MFMA bf16 16x16x32.
//    A-IN-REGISTERS + PER-IB BARRIERS.
//    Block = 256o x 112px (28 x 112 = 3136 exact), 4 waves; wave = 64o x 112px,
//    acc[4][7] = 112 VGPR. Register budget: 112 acc + 32 A-dbuf + temps ~= 190
//    <= 256 at 2 waves/SIMD (the round-3 spill is arithmetically excluded).
//    A (wl): each wave's 64o x 32ch fragment is wave-private & contiguous ->
//    loaded global->REG, double-buffered 1 tap ahead (L2-resident stream;
//    round-1 FETCH=55MB proved cache absorption). A uses NO LDS, NO barriers.
//    B (xg): only LDS tenant. 176-px halo tile staged per ib, double-buffered
//    (2 x 16KB), ONE __syncthreads per ib (9/kernel vs 72) staged a full ib
//    (~5000 cyc) ahead -> drain cost ~0. Compiler gets 9-tap spans to
//    co-schedule A-loads || B-ds_reads || MFMA.
//    Per-tap pad mask = predicated LDS address into a zeroed 16B slot.
//    LDS 32.8KB -> 2 blocks/CU, 8 waves/CU.
__global__ __launch_bounds__(256, 2) void conv_kernel(const short* __restrict__ xg,
                                                      const short* __restrict__ wl,
                                                      const float* __restrict__ biasc,
                                                      float* __restrict__ out) {
    // shorts: B0@0 (8192), B1@8192, zero@16384 (8)
    __shared__ short smem[16400];

    // T1: XCD swizzle, 896 = 8*112 bijective. Consecutive swz share sample b
    // -> wl[b]/xg[b] streams get same-XCD L2 reuse across the 28 px-tiles.
    const int wg  = blockIdx.x;
    const int swz = (wg & 7) * 112 + (wg >> 3);
    const int b   = swz / 28;
    const int pt  = swz - b * 28;

    const int tid = threadIdx.x;
    const int wave = tid >> 6, lane = tid & 63, q = lane >> 4, ln = lane & 15;
    const int P0 = pt * 112;

    const int DOFF[9] = {-57,-56,-55,-1,0,1,55,56,57};

    unsigned vmask[7];
    #pragma unroll
    for (int c = 0; c < 7; ++c) {
        int p = P0 + c*16 + ln;              // always < 3136 (28*112 exact)
        int h = p/56, w = p%56;
        unsigned m = 0;
        #pragma unroll
        for (int tap = 0; tap < 9; ++tap) {
            int h2 = h + tap/3 - 1, w2 = w + tap%3 - 1;
            if ((unsigned)h2 < 56u && (unsigned)w2 < 56u) m |= (1u << tap);
        }
        vmask[c] = m;
    }

    // A fragment source: o row = wave*64 + r*16 + ln, ch chunk q*8. Contiguous
    // 1KB per r-tile -> fully coalesced dwordx4 loads.
    const short* wbase = wl + (size_t)b*KPB_ + (wave*64 + ln)*32 + q*8;
    const short* xbase = xg + (size_t)(b*8)*HW_*32;

    auto stageB = [&](int ib, int buf) {   // 16KB halo [P0-64, P0+192), 4 gll16
        const short* src = xbase + ((long)ib*HW_ + P0 - 64)*32 + tid*8;
        short* dst = &smem[buf*8192 + tid*8];
        #pragma unroll
        for (int r = 0; r < 4; ++r) gll16(src + r*2048, dst + r*2048);
    };

    v8s areg[2][4];                        // A double buffer (indices compile-time)
    auto loadA = [&](int kidx, v8s (&dst)[4]) {
        const short* src = wbase + (size_t)kidx*8192;
        #pragma unroll
        for (int r = 0; r < 4; ++r) dst[r] = *(const v8s*)(src + r*512);
    };

    f32x4 acc[4][7];
    #pragma unroll
    for (int r = 0; r < 4; ++r)
        #pragma unroll
        for (int c = 0; c < 7; ++c) acc[r][c] = (f32x4){0.f,0.f,0.f,0.f};

    if (tid == 0) *(v8s*)&smem[16384] = (v8s){};   // zero slot for masked taps

    stageB(0, 0);
    loadA(0, areg[0]);

    const int bcol0 = (64 + ln)*32 + q*8;          // + buf*8192 + c*512 + doff*32

    for (int ib2 = 0; ib2 < 4; ++ib2) {
        #pragma unroll
        for (int ibu = 0; ibu < 2; ++ibu) {        // ib = ib2*2 + ibu; ib&1 == ibu
            const int ib = ib2*2 + ibu;
            // One barrier per ib: publishes B(ib) (staged a full ib ago,
            // vmcnt(0) drain cost ~0) and frees the other buffer.
            __syncthreads();
            if (ib < 7) stageB(ib + 1, ibu ^ 1);

            #pragma unroll
            for (int tap = 0; tap < 9; ++tap) {
                const int k = ib*9 + tap;
                if (k + 1 < 72) loadA(k + 1, areg[(ibu + tap + 1) & 1]);
                const v8s* A = areg[(ibu + tap) & 1];
                const int base = ibu*8192 + bcol0 + DOFF[tap]*32;
                __builtin_amdgcn_s_setprio(1);
                #pragma unroll
                for (int c = 0; c < 7; ++c) {
                    int off = ((vmask[c] >> tap) & 1) ? (base + c*512) : 16384;
                    v8s v = *(const v8s*)&smem[off];
                    #pragma unroll
                    for (int r = 0; r < 4; ++r)
                        acc[r][c] = __builtin_amdgcn_mfma_f32_16x16x32_bf16(A[r], v, acc[r][c], 0, 0, 0);
                }
                __builtin_amdgcn_s_setprio(0);
            }
        }
    }

    // Epilogue: D col=lane&15 (px), row=q*4+reg (o). No bounds checks needed.
    const int o0 = wave*64 + q*4;
    #pragma unroll
    for (int c = 0; c < 7; ++c) {
        int p = P0 + c*16 + ln;
        float* op = out + (size_t)b * OC_ * HW_ + p;
        #pragma unroll
        for (int r = 0; r < 4; ++r) {
            #pragma unroll
            for (int reg = 0; reg < 4; ++reg) {
                int o = o0 + r*16 + reg;
                op[(size_t)o * HW_] = acc[r][c][reg] + biasc[b*OC_ + o];
            }
        }
    }
}

// ---------------------------------------------------------------------------
extern "C" void kernel_launch(void* const* d_in, const int* in_sizes, int n_in,
                              void* d_out, int out_size, void* d_ws, size_t ws_size,
                              hipStream_t stream) {
    const float* x      = (const float*)d_in[0];
    const float* weight = (const float*)d_in[1];
    const float* bias   = (const float*)d_in[2];
    const float* gate_w = (const float*)d_in[3];
    const float* gate_b = (const float*)d_in[4];
    float* out = (float*)d_out;

    // Workspace layout (bytes):
    //   gap   @ 0       : 32,768
    //   biasc @ 32768   : 32,768
    //   alpha @ 65536   : 1,024
    //   (pad — absorbs conv's B-halo negative overrun, exactly -4 KB at P0=0)
    //   xg    @ 131072  : 32*8*3136*32*2 = 51,380,224
    //   wl    @ 51,511,296 : 32*589824*2 = 37,748,736 (absorbs B-halo tail overrun)
    char* ws = (char*)d_ws;
    float* gap   = (float*)(ws);
    float* biasc = (float*)(ws + 32768);
    float* alpha = (float*)(ws + 65536);
    short* xg    = (short*)(ws + 131072);
    short* wl    = (short*)(ws + 51511296);

    zero_gap_kernel<<<32, 256, 0, stream>>>(gap);
    xcast_kernel   <<<dim3(49, 4, 32), 256, 0, stream>>>(x, xg, gap);
    alpha_kernel   <<<32,  64, 0, stream>>>(gap, gate_w, gate_b, bias, alpha, biasc);
    combine_kernel <<<288, 256, 0, stream>>>(weight, alpha, wl);
    conv_kernel    <<<896, 256, 0, stream>>>(xg, wl, biasc, out);
}

// Round 6
// 389.676 us; speedup vs baseline: 2.0736x; 1.2988x over previous
//
#include <hip/hip_runtime.h>
#include <hip/hip_bf16.h>

// Problem constants
#define B_    32
#define C_    256
#define HW_   3136   // 56*56
#define OC_   256
#define M_    8
#define KPB_  589824 // per-sample wl shorts: 72 kblocks * 8192

typedef short v8s __attribute__((ext_vector_type(8)));   // 8 x bf16 (4 VGPRs)
typedef float f32x4 __attribute__((ext_vector_type(4)));

union bf8pack { v8s v; __hip_bfloat16 h[8]; };

__device__ __forceinline__ void gll16(const short* src, short* dst) {
    __builtin_amdgcn_global_load_lds((const __attribute__((address_space(1))) void*)src,
                                     (__attribute__((address_space(3))) void*)dst, 16, 0, 0);
}

// ---------------------------------------------------------------------------
// 0) zero the gap accumulator (ws is poisoned 0xAA before every launch)
__global__ void zero_gap_kernel(float* __restrict__ gap) {
    gap[blockIdx.x * 256 + threadIdx.x] = 0.f;
}

// ---------------------------------------------------------------------------
// 1) x (f32, BCHW) -> xg (bf16, [b][ib=8][p][32] channel-blocked), fused GAP.
__global__ __launch_bounds__(256) void xcast_kernel(const float* __restrict__ x,
                                                    short* __restrict__ xg,
                                                    float* __restrict__ gap) {
    __shared__ __hip_bfloat16 tile[64][65];   // [channel][pixel], +1 pad
    int b = blockIdx.z, ct = blockIdx.y, pt = blockIdx.x;
    int p0 = pt*64, c0 = ct*64;
    int tp = threadIdx.x & 63, tc = threadIdx.x >> 6;
    const float* xb = x + ((size_t)b*C_ + c0) * HW_ + p0;
    #pragma unroll
    for (int j = 0; j < 16; ++j) {
        int cl = tc + j*4;
        float v = xb[(size_t)cl*HW_ + tp];
        tile[cl][tp] = __float2bfloat16(v);
        float s = v;
        #pragma unroll
        for (int off = 32; off; off >>= 1) s += __shfl_xor(s, off, 64);
        if (tp == 0) atomicAdd(&gap[b*C_ + c0 + cl], s);
    }
    __syncthreads();
    #pragma unroll
    for (int it = 0; it < 2; ++it) {
        int idx = it*256 + threadIdx.x;
        int px = idx >> 3, ck = idx & 7;
        bf8pack pk;
        #pragma unroll
        for (int j = 0; j < 8; ++j) pk.h[j] = tile[ck*8 + j][px];
        int c = c0 + ck*8;
        size_t dst = (((size_t)b*8 + (c >> 5))*HW_ + p0 + px)*32 + (c & 31);
        *(v8s*)(xg + dst) = pk.v;
    }
}

// ---------------------------------------------------------------------------
// 2) Gate softmax + combined bias, fused. One wave per sample. gap holds SUMS.
__global__ void alpha_kernel(const float* __restrict__ gap,
                             const float* __restrict__ gate_w,
                             const float* __restrict__ gate_b,
                             const float* __restrict__ bias,
                             float* __restrict__ alpha,
                             float* __restrict__ biasc) {
    int b = blockIdx.x, lane = threadIdx.x;
    const float inv = 1.0f / HW_;
    float g0 = gap[b*C_ + lane]*inv,       g1 = gap[b*C_ + 64 + lane]*inv;
    float g2 = gap[b*C_ + 128 + lane]*inv, g3 = gap[b*C_ + 192 + lane]*inv;
    float logit[M_];
    #pragma unroll
    for (int m = 0; m < M_; ++m) {
        const float* w = gate_w + m*C_;
        float s = g0*w[lane] + g1*w[64+lane] + g2*w[128+lane] + g3*w[192+lane];
        for (int off = 32; off; off >>= 1) s += __shfl_xor(s, off, 64);
        logit[m] = s + gate_b[m];
    }
    float mx = logit[0];
    #pragma unroll
    for (int m = 1; m < M_; ++m) mx = fmaxf(mx, logit[m]);
    float den = 0.f, e[M_];
    #pragma unroll
    for (int m = 0; m < M_; ++m) { e[m] = __expf(logit[m] - mx); den += e[m]; }
    float am[M_];
    #pragma unroll
    for (int m = 0; m < M_; ++m) am[m] = e[m] / den;
    if (lane < M_) alpha[b*M_ + lane] = am[lane];
    #pragma unroll
    for (int r = 0; r < 4; ++r) {
        int o = r*64 + lane;
        float s = 0.f;
        #pragma unroll
        for (int m = 0; m < M_; ++m) s += am[m] * bias[m*OC_ + o];
        biasc[b*OC_ + o] = s;
    }
}

// ---------------------------------------------------------------------------
// 3) Combine expert kernels: wl[b][ib(8)][tap(9)][o(256)][i_in(32)] bf16.
__global__ __launch_bounds__(256) void combine_kernel(const float* __restrict__ weight,
                                                      const float* __restrict__ alpha,
                                                      short* __restrict__ wl) {
    __shared__ float as[B_*M_];
    as[threadIdx.x] = alpha[threadIdx.x];
    __syncthreads();
    int gc  = blockIdx.x*256 + threadIdx.x;   // [0, 73728)
    int i8  = gc & 3;
    int o   = (gc >> 2) & 255;
    int t2  = gc >> 10;
    int tap = t2 % 9;
    int ib  = t2 / 9;
    int base = o*2304 + (ib*32 + i8*8)*9 + tap;   // + j*9
    float wv[M_][8];
    #pragma unroll
    for (int m = 0; m < M_; ++m)
        #pragma unroll
        for (int j = 0; j < 8; ++j)
            wv[m][j] = weight[(size_t)m*589824 + base + j*9];
    for (int b = 0; b < B_; ++b) {
        bf8pack pk;
        #pragma unroll
        for (int j = 0; j < 8; ++j) {
            float s = 0.f;
            #pragma unroll
            for (int m = 0; m < M_; ++m) s += as[b*M_+m] * wv[m][j];
            pk.h[j] = __float2bfloat16(s);
        }
        *(v8s*)(wl + (size_t)b*KPB_ + (size_t)gc*8) = pk.v;
    }
}

// ---------------------------------------------------------------------------
// 4) Implicit-GEMM conv, MFMA bf16 16x16x32.  BARRIER-FREE TAP LOOP.
//    Block = 128o x 224px (2ot x 14pt x 32b = 896 = 8*112 bijective swz),
//    4 waves (o_half x p_half); wave = 64o x 112px, acc[4][7] = 112.
//    A (wl): global->REG, 4 slots x 4 v8s (64 VGPR), prefetch distance 3
//    (~700-900 cyc cover >= L2-miss latency -- fixes round-5's 1-deep stall).
//    Fully unrolled (ib%4, tap) so all slot indices are compile-time.
//    B (xg): LDS only. 384-px halo, 2 x 24KB dbuf, staged once per ib;
//    ONE __syncthreads per ib (8 total vs round-1's 72). Within the 9-tap
//    span there are NO barriers: the compiler's fine-grained lgkmcnt/vmcnt
//    lets each wave issue next-tap B-ds_reads + A-loads under current-tap
//    MFMAs -- the within-wave overlap rounds 1/5 structurally forbade.
//    Register budget: 112 acc(AGPR) + 64 areg + ~40 misc ~= 216 < 256 @
//    __launch_bounds__(256,2). LDS 48KB -> 2 blocks/CU, 8 waves/CU.
__global__ __launch_bounds__(256, 2) void conv_kernel(const short* __restrict__ xg,
                                                      const short* __restrict__ wl,
                                                      const float* __restrict__ biasc,
                                                      float* __restrict__ out) {
    __shared__ short smem[24576];  // 48 KB: B0@0, B1@12288 (shorts)

    // T1: XCD swizzle, 896 = 8*112 bijective. Consecutive swz share sample b.
    const int wg  = blockIdx.x;
    const int swz = (wg & 7) * 112 + (wg >> 3);
    const int b   = swz / 28;
    const int rm  = swz - b * 28;
    const int ot  = rm / 14;
    const int pt  = rm - ot * 14;

    const int tid = threadIdx.x;
    const int wave = tid >> 6, lane = tid & 63, q = lane >> 4, ln = lane & 15;
    const int o_half = wave >> 1, p_half = wave & 1;
    const int P0 = pt * 224;

    const int DOFF[9] = {-57,-56,-55,-1,0,1,55,56,57};

    unsigned vmask[7];
    #pragma unroll
    for (int c = 0; c < 7; ++c) {
        int p = P0 + p_half*112 + c*16 + ln;     // always < 3136 (14*224 exact)
        int h = p/56, w = p%56;
        unsigned m = 0;
        #pragma unroll
        for (int tap = 0; tap < 9; ++tap) {
            int h2 = h + tap/3 - 1, w2 = w + tap%3 - 1;
            if ((unsigned)h2 < 56u && (unsigned)w2 < 56u) m |= (1u << tap);
        }
        vmask[c] = m;
    }

    // A fragment source: kblock layout [o(256)][ch(32)]; wave reads o rows
    // o_base + r*16 + ln, ch chunk q*8 -> contiguous 1KB per r (dwordx4).
    const short* wbase = wl + (size_t)b*KPB_ + ((ot*128 + o_half*64 + ln)*32 + q*8);
    const short* xbase = xg + (size_t)(b*8)*HW_*32;

    auto stageB = [&](int ib, int buf) {   // 24KB halo [P0-64, P0+320), 6 gll16
        const short* src = xbase + ((long)ib*HW_ + P0 - 64)*32 + tid*8;
        short* dst = &smem[buf*12288 + tid*8];
        #pragma unroll
        for (int r = 0; r < 6; ++r) gll16(src + r*2048, dst + r*2048);
    };

    v8s areg[4][4];                        // 4 slots (distance-3 prefetch)
    auto loadA = [&](int kidx, v8s (&dst)[4]) {
        const short* src = wbase + (size_t)kidx*8192;
        #pragma unroll
        for (int r = 0; r < 4; ++r) dst[r] = *(const v8s*)(src + r*512);
    };

    f32x4 acc[4][7];
    #pragma unroll
    for (int r = 0; r < 4; ++r)
        #pragma unroll
        for (int c = 0; c < 7; ++c) acc[r][c] = (f32x4){0.f,0.f,0.f,0.f};

    // Prologue: B(0) + A slots 0..2. The ib=0 top barrier drains all.
    stageB(0, 0);
    loadA(0, areg[0]);
    loadA(1, areg[1]);
    loadA(2, areg[2]);

    const int bcol0 = (64 + p_half*112 + ln)*32 + q*8;  // + buf*12288 + c*512 + doff*32
    const v8s vzero = {};

    for (int io = 0; io < 2; ++io) {
        #pragma unroll
        for (int i4 = 0; i4 < 4; ++i4) {
            const int ib = io*4 + i4;          // ib&1 == i4&1; ib&3 == i4 (io*4%4==0)
            // One barrier per ib: publishes B(ib) (staged 9 taps ago) and
            // frees the other buffer. vmcnt(0) drain: in-flight A prefetches
            // are ~2-3 taps old -> near-complete; cost once per 9 taps.
            __syncthreads();
            if (ib < 7) stageB(ib + 1, (i4 + 1) & 1);

            #pragma unroll
            for (int tap = 0; tap < 9; ++tap) {
                const int k = ib*9 + tap;                 // k&3 == (i4*9+tap)&3
                if (k + 3 < 72) loadA(k + 3, areg[(i4*9 + tap + 3) & 3]);
                const v8s* A = areg[(i4*9 + tap) & 3];
                const int base = (i4 & 1)*12288 + bcol0 + DOFF[tap]*32;
                #pragma unroll
                for (int c = 0; c < 7; ++c) {
                    v8s v = *(const v8s*)&smem[base + c*512];
                    v8s bf = ((vmask[c] >> tap) & 1) ? v : vzero;
                    #pragma unroll
                    for (int r = 0; r < 4; ++r)
                        acc[r][c] = __builtin_amdgcn_mfma_f32_16x16x32_bf16(A[r], bf, acc[r][c], 0, 0, 0);
                }
            }
        }
    }

    // Epilogue: D col=lane&15 (px), row=q*4+reg (o). Exact tiling, no checks.
    const int o0 = ot*128 + o_half*64 + q*4;
    #pragma unroll
    for (int c = 0; c < 7; ++c) {
        int p = P0 + p_half*112 + c*16 + ln;
        float* op = out + (size_t)b * OC_ * HW_ + p;
        #pragma unroll
        for (int r = 0; r < 4; ++r) {
            #pragma unroll
            for (int reg = 0; reg < 4; ++reg) {
                int o = o0 + r*16 + reg;
                op[(size_t)o * HW_] = acc[r][c][reg] + biasc[b*OC_ + o];
            }
        }
    }
}

// ---------------------------------------------------------------------------
extern "C" void kernel_launch(void* const* d_in, const int* in_sizes, int n_in,
                              void* d_out, int out_size, void* d_ws, size_t ws_size,
                              hipStream_t stream) {
    const float* x      = (const float*)d_in[0];
    const float* weight = (const float*)d_in[1];
    const float* bias   = (const float*)d_in[2];
    const float* gate_w = (const float*)d_in[3];
    const float* gate_b = (const float*)d_in[4];
    float* out = (float*)d_out;

    // Workspace layout (bytes):
    //   gap   @ 0       : 32,768
    //   biasc @ 32768   : 32,768
    //   alpha @ 65536   : 1,024
    //   (pad — absorbs conv's B-halo negative overrun, up to -4 KB at P0=0)
    //   xg    @ 131072  : 32*8*3136*32*2 = 51,380,224
    //   wl    @ 51,511,296 : 32*589824*2 = 37,748,736 (absorbs B-halo tail overrun)
    char* ws = (char*)d_ws;
    float* gap   = (float*)(ws);
    float* biasc = (float*)(ws + 32768);
    float* alpha = (float*)(ws + 65536);
    short* xg    = (short*)(ws + 131072);
    short* wl    = (short*)(ws + 51511296);

    zero_gap_kernel<<<32, 256, 0, stream>>>(gap);
    xcast_kernel   <<<dim3(49, 4, 32), 256, 0, stream>>>(x, xg, gap);
    alpha_kernel   <<<32,  64, 0, stream>>>(gap, gate_w, gate_b, bias, alpha, biasc);
    combine_kernel <<<288, 256, 0, stream>>>(weight, alpha, wl);
    conv_kernel    <<<896, 256, 0, stream>>>(xg, wl, biasc, out);
}